// Round 8
// baseline (219.202 us; speedup 1.0000x reference)
//
#include <hip/hip_runtime.h>

// out[s,a] = values[index[s,a]]
// index: 16384*2048 int32 (128 MiB), values: 100 fp32 (400 B), out: fp32 (128 MiB)
// Irreducible traffic: 268.4 MB -> ~42 us floor @ ~6.3 TB/s mixed-stream.
// FINAL (= R5, best measured 217.25 us total; kernel ~48 us):
//   flat one-int4-per-thread, block=1024, grid=8192, shared svals + barrier,
//   nontemporal load/store.
// Search record: grid-stride(228.0) > flat2/thr(221.3) > flat256(218.8)
//   = per-wave-copy(218.8) > flat1024(217.25). Max TLP + one access pair per
//   thread wins; ILP batching and barrier removal both regress.

constexpr int VOCAB = 100;

typedef int   vint4   __attribute__((ext_vector_type(4)));
typedef float vfloat4 __attribute__((ext_vector_type(4)));

__global__ __launch_bounds__(1024) void gather_kernel(
    const vint4* __restrict__ idx4,
    const float* __restrict__ vals,
    vfloat4* __restrict__ out4)
{
    __shared__ float svals[VOCAB];
    if (threadIdx.x < VOCAB) svals[threadIdx.x] = vals[threadIdx.x];
    __syncthreads();

    const int t = blockIdx.x * blockDim.x + threadIdx.x;  // one int4 per thread

    vint4 v = __builtin_nontemporal_load(&idx4[t]);
    vfloat4 o = { svals[v.x], svals[v.y], svals[v.z], svals[v.w] };
    __builtin_nontemporal_store(o, &out4[t]);
}

extern "C" void kernel_launch(void* const* d_in, const int* in_sizes, int n_in,
                              void* d_out, int out_size, void* d_ws, size_t ws_size,
                              hipStream_t stream) {
    const int*   idx  = (const int*)d_in[0];     // 16384*2048 int32
    const float* vals = (const float*)d_in[1];   // 100 fp32
    float*       out  = (float*)d_out;           // fp32

    int n  = in_sizes[0];                        // 33554432
    int n4 = n / 4;                              // 8388608 = 8192 * 1024

    const int block = 1024;
    const int grid  = n4 / block;                // 8192 blocks, exact cover

    gather_kernel<<<grid, block, 0, stream>>>(
        (const vint4*)idx, vals, (vfloat4*)out);
}